// Round 1
// 592.914 us; speedup vs baseline: 1.1348x; 1.1348x over previous
//
#include <hip/hip_runtime.h>

// MultiHeadAttention fused block, MI355X gfx950.
// B=256, NA=128, E=1024, H=16, HD=64. M = B*NA = 32768 rows.
//
// Pipeline:
//   K0: in_w fp32 -> bf16                   (Wb)
//   K1: LN1(x) -> bf16                      (xnb)
//   K2: MFMA GEMM xnb @ Wb^T + bias -> Qb(.125 folded), Kb, Vb (bf16)
//       R1: 256x256 tile, BK=64, 8-phase counted-vmcnt schedule (T1+T2+T3+T4+T5)
//   K3: per-group attention (4096 groups of 128x64), MFMA QK^T + softmax + PV
//       -> attnb (bf16, overlays xnb), avg_w -> d_out tail
//   K4: recompute LN1 stats, residual + LN2 -> d_out
//
// Workspace layout (bytes):
//   [0,            67108864)  xnb / attnb (bf16, 33554432 elems)  -- reused
//   [67108864,    134217728)  Qb
//   [134217728,   201326592)  Kb
//   [201326592,   268435456)  Vb
//   [268435456,   274726912)  Wb (3072*1024 bf16)
// Total 274.7 MB.

typedef __attribute__((ext_vector_type(4))) float float4v;
typedef __attribute__((ext_vector_type(4))) int   int4v;
typedef __attribute__((ext_vector_type(8))) short short8v;
typedef __attribute__((ext_vector_type(4))) short short4v;

#define LN_EPS 1e-5f

// Direct global->LDS DMA, 16 B per lane. LDS base must be wave-uniform;
// hardware writes base + lane*16.
#define GLL(g, l) __builtin_amdgcn_global_load_lds( \
    (const __attribute__((address_space(1))) unsigned int*)(g), \
    (__attribute__((address_space(3))) unsigned int*)(l), 16, 0, 0)

__device__ __forceinline__ unsigned short f2bf(float f) {
    unsigned int u = __float_as_uint(f);
    u += 0x7FFFu + ((u >> 16) & 1u);   // round-to-nearest-even
    return (unsigned short)(u >> 16);
}
__device__ __forceinline__ float bf2f(unsigned short h) {
    return __uint_as_float(((unsigned int)h) << 16);
}

// ---------------------------------------------------------------- K0: W->bf16
__global__ __launch_bounds__(256) void k0_w_to_bf16(const float* __restrict__ w,
                                                    unsigned short* __restrict__ wb) {
    int idx = blockIdx.x * 256 + threadIdx.x;      // one thread per 8 elems
    const float4v* src = (const float4v*)w;
    float4v a = src[idx * 2];
    float4v b = src[idx * 2 + 1];
    short8v o;
    o[0] = (short)f2bf(a[0]); o[1] = (short)f2bf(a[1]);
    o[2] = (short)f2bf(a[2]); o[3] = (short)f2bf(a[3]);
    o[4] = (short)f2bf(b[0]); o[5] = (short)f2bf(b[1]);
    o[6] = (short)f2bf(b[2]); o[7] = (short)f2bf(b[3]);
    *((short8v*)wb + idx) = o;
}

// --------------------------------------------------------- block reduction
__device__ __forceinline__ void block_reduce_2(float& s, float& s2, float* red) {
    #pragma unroll
    for (int off = 32; off > 0; off >>= 1) {
        s  += __shfl_xor(s, off, 64);
        s2 += __shfl_xor(s2, off, 64);
    }
    __syncthreads();                      // also protects re-use of red
    if ((threadIdx.x & 63) == 0) {
        red[(threadIdx.x >> 6) * 2]     = s;
        red[(threadIdx.x >> 6) * 2 + 1] = s2;
    }
    __syncthreads();
    s  = red[0] + red[2] + red[4] + red[6];
    s2 = red[1] + red[3] + red[5] + red[7];
}

// ---------------------------------------------------------------- K1: LN1
__global__ __launch_bounds__(256) void k1_ln1(const float* __restrict__ x,
                                              const float* __restrict__ w1,
                                              const float* __restrict__ b1,
                                              unsigned short* __restrict__ xnb) {
    __shared__ float red[8];
    int row = blockIdx.x;
    int tid = threadIdx.x;
    float4v xv = ((const float4v*)(x + (size_t)row * 1024))[tid];
    float s  = xv[0] + xv[1] + xv[2] + xv[3];
    float s2 = xv[0]*xv[0] + xv[1]*xv[1] + xv[2]*xv[2] + xv[3]*xv[3];
    block_reduce_2(s, s2, red);
    float mean = s * (1.0f / 1024.0f);
    float var  = s2 * (1.0f / 1024.0f) - mean * mean;
    float rs   = rsqrtf(var + LN_EPS);
    float4v wv = ((const float4v*)w1)[tid];
    float4v bv = ((const float4v*)b1)[tid];
    short4v o;
    #pragma unroll
    for (int c = 0; c < 4; ++c)
        o[c] = (short)f2bf((xv[c] - mean) * rs * wv[c] + bv[c]);
    ((short4v*)(xnb + (size_t)row * 1024))[tid] = o;
}

// ---------------------------------------------------------------- K2: QKV GEMM
// C[m][n] = sum_k A[m][k]*W[n][k] + bias[n]; A:32768x1024 bf16, W:3072x1024 bf16.
// 256x256 tile, BK=64, 8 waves (2M x 4N), per-wave 128x64 output (acc[8][4]).
// LDS 128 KiB: sA[2]/sB[2] double-buffered [256][64] bf16 K-tiles.
// T2 swizzle: logical (row, colByte cb) lives at physical cb ^ ((row&7)<<4);
// global_load_lds writes linearly, so the global SOURCE col is pre-XORed
// (rule #21: linear dest + inverse-swz source + swz read; XOR = involution).
// Schedule (derived, hazard-checked): 8 phases/iter, 2 K-tiles (T(2i) buf0
// phases 1-4, T(2i+1) buf1 phases 5-8). Stages: ph1/2 T(2i+1).A -> buf1,
// ph3/4 T(2i+2).B -> buf0, ph5/6 T(2i+2).A -> buf0, ph7/8 T(2i+3).B -> buf1.
// Every stage target was last read >=1 barrier earlier; vmcnt(4) at ph4/ph8
// guarantees everything except the 2 newest half-tiles has landed (exactly
// what the next 4 phases read). Never vmcnt(0) in steady state.
__global__ __launch_bounds__(512, 2) void k2_qkv_gemm(const unsigned short* __restrict__ A,
                                                      const unsigned short* __restrict__ W,
                                                      const float* __restrict__ bias,
                                                      unsigned short* __restrict__ Qb,
                                                      unsigned short* __restrict__ Kb,
                                                      unsigned short* __restrict__ Vb) {
    __shared__ unsigned short smem[65536];           // 128 KiB (also epilogue C-tile)
    unsigned short* sA0 = smem;                      // [256][64] bf16, even K-tile
    unsigned short* sA1 = smem + 16384;              // odd K-tile
    unsigned short* sB0 = smem + 32768;
    unsigned short* sB1 = smem + 49152;

    int bid = blockIdx.x;
    int wg  = (bid & 7) * 192 + (bid >> 3);          // XCD swizzle, 1536 % 8 == 0 (bijective)
    int nT  = wg % 12;                               // N-fastest: 12 consecutive share A panel
    int mT  = wg / 12;
    int rowBase = mT * 256;
    int colBase = nT * 256;

    int tid  = threadIdx.x;
    int lane = tid & 63;
    int wave = tid >> 6;
    int wm = wave >> 2, wn = wave & 3;               // 2 x 4 wave grid
    int q4 = lane >> 4, l15 = lane & 15;

    // staging: thread t stages physical LDS bytes [r*8192 + t*16, +16):
    // row = r*64 + t/8, physBy = (t&7)*16; source colByte = physBy ^ ((row&7)<<4).
    int lrow_s = tid >> 3;                           // row within 64-row round
    int srcCol = ((tid & 7) * 16) ^ ((lrow_s & 7) << 4);
    const char* aSrc = (const char*)A + ((size_t)(rowBase + lrow_s) << 11) + srcCol;
    const char* wSrc = (const char*)W + ((size_t)(colBase + lrow_s) << 11) + srcCol;
    int waveOff = wave * 1024;

    // fragment read offsets (bytes): row*128 + ((kk*64 + q4*16) ^ ((l15&7)<<4))
    int xorv = (l15 & 7) << 4;
    int aRow = (wm * 128 + l15) * 128;
    int bRow = (wn * 64 + l15) * 128;
    int bc0 = (q4 * 16) ^ xorv;                      // kk = 0
    int bc1 = (64 + q4 * 16) ^ xorv;                 // kk = 1

    float bv[4];
    #pragma unroll
    for (int n = 0; n < 4; ++n) bv[n] = bias[colBase + wn * 64 + n * 16 + l15];

    float4v acc[8][4];
    #pragma unroll
    for (int t = 0; t < 8; ++t)
        #pragma unroll
        for (int n = 0; n < 4; ++n) acc[t][n] = (float4v){0.f, 0.f, 0.f, 0.f};

#define STAGE_HALF(lds, src, ktB_, h) do { \
    GLL((src) + (ktB_) + (2*(h))   * 131072, (char*)(lds) + (2*(h))   * 8192 + waveOff); \
    GLL((src) + (ktB_) + (2*(h)+1) * 131072, (char*)(lds) + (2*(h)+1) * 8192 + waveOff); \
} while (0)
#define LDB(SB) do { \
    const char* c_ = (const char*)(SB); \
    _Pragma("unroll") \
    for (int n = 0; n < 4; ++n) { \
        bf[n][0] = *(const short8v*)(c_ + bRow + n * 2048 + bc0); \
        bf[n][1] = *(const short8v*)(c_ + bRow + n * 2048 + bc1); \
    } \
} while (0)
#define LDA2(SA, T0_) do { \
    const char* c_ = (const char*)(SA); \
    af[0][0] = *(const short8v*)(c_ + aRow + (T0_)     * 2048 + bc0); \
    af[0][1] = *(const short8v*)(c_ + aRow + (T0_)     * 2048 + bc1); \
    af[1][0] = *(const short8v*)(c_ + aRow + (T0_ + 1) * 2048 + bc0); \
    af[1][1] = *(const short8v*)(c_ + aRow + (T0_ + 1) * 2048 + bc1); \
} while (0)
#define MFMA8(T0_) do { \
    __builtin_amdgcn_s_setprio(1); \
    _Pragma("unroll") \
    for (int n = 0; n < 4; ++n) { \
        acc[T0_][n]     = __builtin_amdgcn_mfma_f32_16x16x32_bf16(af[0][0], bf[n][0], acc[T0_][n], 0, 0, 0); \
        acc[T0_][n]     = __builtin_amdgcn_mfma_f32_16x16x32_bf16(af[0][1], bf[n][1], acc[T0_][n], 0, 0, 0); \
        acc[T0_ + 1][n] = __builtin_amdgcn_mfma_f32_16x16x32_bf16(af[1][0], bf[n][0], acc[T0_ + 1][n], 0, 0, 0); \
        acc[T0_ + 1][n] = __builtin_amdgcn_mfma_f32_16x16x32_bf16(af[1][1], bf[n][1], acc[T0_ + 1][n], 0, 0, 0); \
    } \
    __builtin_amdgcn_s_setprio(0); \
} while (0)
#define PH_SYNC do { __builtin_amdgcn_s_barrier(); asm volatile("s_waitcnt lgkmcnt(0)"); } while (0)
#define PH_END  __builtin_amdgcn_s_barrier()

    // prologue: T0 full (A+B) + T1.B; leave T1.B (4 loads) in flight
    STAGE_HALF(sA0, aSrc, 0, 0);
    STAGE_HALF(sA0, aSrc, 0, 1);
    STAGE_HALF(sB0, wSrc, 0, 0);
    STAGE_HALF(sB0, wSrc, 0, 1);
    STAGE_HALF(sB1, wSrc, 128, 0);
    STAGE_HALF(sB1, wSrc, 128, 1);
    asm volatile("s_waitcnt vmcnt(4)");
    __builtin_amdgcn_s_barrier();

    short8v af[2][2], bf[4][2];

    #pragma unroll 1
    for (int i = 0; i < 8; ++i) {
        int ktB = i << 8;                 // byte K-offset of T(2i) (tile = 128 B)
        bool nl = (i < 7);
        // PH1: T(2i) quad0 from buf0; stage T(2i+1).A0 -> buf1 (buf1.A free since prev ph8)
        LDB(sB0); LDA2(sA0, 0);
        STAGE_HALF(sA1, aSrc, ktB + 128, 0);
        PH_SYNC; MFMA8(0); PH_END;
        // PH2: quad1; stage T(2i+1).A1
        LDA2(sA0, 2);
        STAGE_HALF(sA1, aSrc, ktB + 128, 1);
        PH_SYNC; MFMA8(2); PH_END;
        // PH3: quad2; stage T(2i+2).B0 (buf0.B read only in ph1)
        LDA2(sA0, 4);
        if (nl) STAGE_HALF(sB0, wSrc, ktB + 256, 0);
        PH_SYNC; MFMA8(4); PH_END;
        // PH4: quad3; stage T(2i+2).B1; counted wait -> T(2i+1) fully landed
        LDA2(sA0, 6);
        if (nl) { STAGE_HALF(sB0, wSrc, ktB + 256, 1); asm volatile("s_waitcnt vmcnt(4)"); }
        else    { asm volatile("s_waitcnt vmcnt(0)"); }
        PH_SYNC; MFMA8(6); PH_END;
        // PH5: T(2i+1) quad0 from buf1; stage T(2i+2).A0 (buf0.A free after ph4)
        LDB(sB1); LDA2(sA1, 0);
        if (nl) STAGE_HALF(sA0, aSrc, ktB + 256, 0);
        PH_SYNC; MFMA8(0); PH_END;
        // PH6: quad1; stage T(2i+2).A1
        LDA2(sA1, 2);
        if (nl) STAGE_HALF(sA0, aSrc, ktB + 256, 1);
        PH_SYNC; MFMA8(2); PH_END;
        // PH7: quad2; stage T(2i+3).B0 (buf1.B read only in ph5)
        LDA2(sA1, 4);
        if (nl) STAGE_HALF(sB1, wSrc, ktB + 384, 0);
        PH_SYNC; MFMA8(4); PH_END;
        // PH8: quad3; stage T(2i+3).B1; counted wait -> T(2i+2) fully landed
        LDA2(sA1, 6);
        if (nl) { STAGE_HALF(sB1, wSrc, ktB + 384, 1); asm volatile("s_waitcnt vmcnt(4)"); }
        PH_SYNC; MFMA8(6); PH_END;
    }
#undef STAGE_HALF
#undef LDB
#undef LDA2
#undef MFMA8
#undef PH_SYNC
#undef PH_END

    // Epilogue: bias+scale, bf16 C-tile through LDS for coalesced 16B stores.
    __syncthreads();
    float scale = (colBase < 1024) ? 0.125f : 1.0f;
    unsigned short* outb = (colBase < 1024) ? Qb : (colBase < 2048) ? Kb : Vb;
    int lcol = colBase & 1023;
    #pragma unroll
    for (int t = 0; t < 8; ++t)
        #pragma unroll
        for (int n = 0; n < 4; ++n)
            #pragma unroll
            for (int g = 0; g < 4; ++g)
                smem[(wm * 128 + t * 16 + q4 * 4 + g) * 256 + wn * 64 + n * 16 + l15] =
                    f2bf((acc[t][n][g] + bv[n]) * scale);
    __syncthreads();
    #pragma unroll
    for (int k = 0; k < 16; ++k) {
        int r = k * 16 + (tid >> 5);                 // half-wave = one 512B row chunk
        short8v v = *(const short8v*)((const char*)smem + r * 512 + (tid & 31) * 16);
        *(short8v*)((char*)(outb + (size_t)(rowBase + r) * 1024 + lcol) + (tid & 31) * 16) = v;
    }
}

// ---------------------------------------------------------------- K3: attention
// One block per group j (4096). Element [j][i][d] lives at flat i*262144 + j*64 + d.
#define QK_S 72
#define P_S  136
#define VT_S 136
__global__ __launch_bounds__(256) void k3_attn(const unsigned short* __restrict__ Qb,
                                               const unsigned short* __restrict__ Kb,
                                               const unsigned short* __restrict__ Vb,
                                               unsigned short* __restrict__ attnb,
                                               float* __restrict__ avgw) {
    __shared__ unsigned short region0[128 * QK_S * 2];  // sQ | sK, later sP (128*136 fits)
    __shared__ unsigned short sVt[64 * VT_S];
    __shared__ float wred[2][2][128];                   // [max/sum][wn][row]
    __shared__ float colsum[128];
    unsigned short* sQ = region0;
    unsigned short* sK = region0 + 128 * QK_S;
    unsigned short* sP = region0;

    int j = blockIdx.x;
    int tid = threadIdx.x;
    int lane = tid & 63;
    int wave = tid >> 6;
    int wm = wave >> 1, wn = wave & 1;
    int q4 = lane >> 4, l15 = lane & 15;
    size_t base = (size_t)j * 64;

    if (tid < 128) colsum[tid] = 0.f;
    for (int idx = tid; idx < 1024; idx += 256) {       // Q,K: 128 rows x 64, 8-elem chunks
        int i = idx >> 3, seg = (idx & 7) * 8;
        *(int4v*)(sQ + i * QK_S + seg) = *(const int4v*)(Qb + base + (size_t)i * 262144 + seg);
        *(int4v*)(sK + i * QK_S + seg) = *(const int4v*)(Kb + base + (size_t)i * 262144 + seg);
    }
    for (int idx = tid; idx < 1024; idx += 256) {       // V: 16B vector reads, LDS transpose
        int m = idx >> 3, seg = (idx & 7) * 8;
        short8v v = *(const short8v*)(Vb + base + (size_t)m * 262144 + seg);
        #pragma unroll
        for (int t = 0; t < 8; ++t)
            sVt[(seg + t) * VT_S + m] = (unsigned short)v[t];
    }
    __syncthreads();

    // Phase A: S = Q K^T  (wave (wm,wn) covers rows wm*64.., cols wn*64..)
    float4v zero4 = {0.f, 0.f, 0.f, 0.f};
    float4v S[4][4];
    #pragma unroll
    for (int a = 0; a < 4; ++a)
        #pragma unroll
        for (int b = 0; b < 4; ++b) S[a][b] = zero4;
    #pragma unroll
    for (int ks = 0; ks < 2; ++ks) {
        short8v qf[4], kf[4];
        #pragma unroll
        for (int t = 0; t < 4; ++t) {
            qf[t] = *(const short8v*)(sQ + (wm * 64 + t * 16 + l15) * QK_S + q4 * 8 + ks * 32);
            kf[t] = *(const short8v*)(sK + (wn * 64 + t * 16 + l15) * QK_S + q4 * 8 + ks * 32);
        }
        #pragma unroll
        for (int tm = 0; tm < 4; ++tm)
            #pragma unroll
            for (int tn = 0; tn < 4; ++tn)
                S[tm][tn] = __builtin_amdgcn_mfma_f32_16x16x32_bf16(qf[tm], kf[tn], S[tm][tn], 0, 0, 0);
    }

    // Row max (wave-local 64 cols -> cross-wave via LDS)
    float rmax[4][4];
    #pragma unroll
    for (int tm = 0; tm < 4; ++tm)
        #pragma unroll
        for (int g = 0; g < 4; ++g)
            rmax[tm][g] = fmaxf(fmaxf(S[tm][0][g], S[tm][1][g]), fmaxf(S[tm][2][g], S[tm][3][g]));
    #pragma unroll
    for (int off = 1; off <= 8; off <<= 1)
        #pragma unroll
        for (int tm = 0; tm < 4; ++tm)
            #pragma unroll
            for (int g = 0; g < 4; ++g)
                rmax[tm][g] = fmaxf(rmax[tm][g], __shfl_xor(rmax[tm][g], off, 64));
    if (l15 == 0) {
        #pragma unroll
        for (int tm = 0; tm < 4; ++tm)
            #pragma unroll
            for (int g = 0; g < 4; ++g)
                wred[0][wn][wm * 64 + tm * 16 + q4 * 4 + g] = rmax[tm][g];
    }
    __syncthreads();

    // exp + row sum
    float rsum[4][4];
    #pragma unroll
    for (int tm = 0; tm < 4; ++tm)
        #pragma unroll
        for (int g = 0; g < 4; ++g) {
            int r = wm * 64 + tm * 16 + q4 * 4 + g;
            float rm = fmaxf(wred[0][0][r], wred[0][1][r]);
            float t0 = 0.f;
            #pragma unroll
            for (int tn = 0; tn < 4; ++tn) {
                float e = __expf(S[tm][tn][g] - rm);
                S[tm][tn][g] = e;
                t0 += e;
            }
            rsum[tm][g] = t0;
        }
    #pragma unroll
    for (int off = 1; off <= 8; off <<= 1)
        #pragma unroll
        for (int tm = 0; tm < 4; ++tm)
            #pragma unroll
            for (int g = 0; g < 4; ++g)
                rsum[tm][g] += __shfl_xor(rsum[tm][g], off, 64);
    if (l15 == 0) {
        #pragma unroll
        for (int tm = 0; tm < 4; ++tm)
            #pragma unroll
            for (int g = 0; g < 4; ++g)
                wred[1][wn][wm * 64 + tm * 16 + q4 * 4 + g] = rsum[tm][g];
    }
    __syncthreads();

    // normalize w = e / rowsum
    #pragma unroll
    for (int tm = 0; tm < 4; ++tm)
        #pragma unroll
        for (int g = 0; g < 4; ++g) {
            int r = wm * 64 + tm * 16 + q4 * 4 + g;
            float inv = 1.0f / (wred[1][0][r] + wred[1][1][r]);
            #pragma unroll
            for (int tn = 0; tn < 4; ++tn) S[tm][tn][g] *= inv;
        }

    // avg_w column sums (sum over query rows)
    float cs[4];
    #pragma unroll
    for (int tn = 0; tn < 4; ++tn) {
        float t0 = 0.f;
        #pragma unroll
        for (int tm = 0; tm < 4; ++tm)
            #pragma unroll
            for (int g = 0; g < 4; ++g) t0 += S[tm][tn][g];
        cs[tn] = t0;
    }
    #pragma unroll
    for (int off = 16; off <= 32; off <<= 1)
        #pragma unroll
        for (int tn = 0; tn < 4; ++tn) cs[tn] += __shfl_xor(cs[tn], off, 64);
    if (lane < 16) {
        #pragma unroll
        for (int tn = 0; tn < 4; ++tn)
            atomicAdd(&colsum[wn * 64 + tn * 16 + lane], cs[tn]);
    }
    __syncthreads();   // sQ/sK reads & colsum atomics complete block-wide

    // write P (bf16) into region0 (aliases sQ/sK — safe now)
    #pragma unroll
    for (int tm = 0; tm < 4; ++tm)
        #pragma unroll
        for (int tn = 0; tn < 4; ++tn)
            #pragma unroll
            for (int g = 0; g < 4; ++g)
                sP[(wm * 64 + tm * 16 + q4 * 4 + g) * P_S + wn * 64 + tn * 16 + l15] = f2bf(S[tm][tn][g]);
    __syncthreads();

    if (tid < 128) avgw[(size_t)j * 128 + tid] = colsum[tid] * (1.0f / 16.0f);

    // Phase C: O = P V (via transposed V). Wave covers rows wm*64.., cols wn*32..
    float4v O[4][2];
    #pragma unroll
    for (int a = 0; a < 4; ++a) { O[a][0] = zero4; O[a][1] = zero4; }
    #pragma unroll
    for (int ks = 0; ks < 4; ++ks) {
        short8v pf[4], vf[2];
        #pragma unroll
        for (int t = 0; t < 4; ++t)
            pf[t] = *(const short8v*)(sP + (wm * 64 + t * 16 + l15) * P_S + q4 * 8 + ks * 32);
        #pragma unroll
        for (int t = 0; t < 2; ++t)
            vf[t] = *(const short8v*)(sVt + (wn * 32 + t * 16 + l15) * VT_S + q4 * 8 + ks * 32);
        #pragma unroll
        for (int tm = 0; tm < 4; ++tm)
            #pragma unroll
            for (int tn = 0; tn < 2; ++tn)
                O[tm][tn] = __builtin_amdgcn_mfma_f32_16x16x32_bf16(pf[tm], vf[tn], O[tm][tn], 0, 0, 0);
    }
    #pragma unroll
    for (int tm = 0; tm < 4; ++tm)
        #pragma unroll
        for (int tn = 0; tn < 2; ++tn)
            #pragma unroll
            for (int g = 0; g < 4; ++g) {
                int i = wm * 64 + tm * 16 + q4 * 4 + g;
                int d = wn * 32 + tn * 16 + l15;
                attnb[base + (size_t)i * 262144 + d] = f2bf(O[tm][tn][g]);
            }
}

// ---------------------------------------------------------------- K4: residual + LN2
__global__ __launch_bounds__(256) void k4_ln2(const float* __restrict__ x,
                                              const float* __restrict__ w1,
                                              const float* __restrict__ b1,
                                              const unsigned short* __restrict__ attnb,
                                              const float* __restrict__ w2,
                                              const float* __restrict__ b2,
                                              float* __restrict__ out) {
    __shared__ float red[8];
    int row = blockIdx.x;
    int tid = threadIdx.x;
    float4v xv = ((const float4v*)(x + (size_t)row * 1024))[tid];
    float s  = xv[0] + xv[1] + xv[2] + xv[3];
    float s2 = xv[0]*xv[0] + xv[1]*xv[1] + xv[2]*xv[2] + xv[3]*xv[3];
    block_reduce_2(s, s2, red);
    float mean = s * (1.0f / 1024.0f);
    float var  = s2 * (1.0f / 1024.0f) - mean * mean;
    float rs   = rsqrtf(var + LN_EPS);
    float4v wv = ((const float4v*)w1)[tid];
    float4v bv = ((const float4v*)b1)[tid];
    short4v av = ((const short4v*)(attnb + (size_t)row * 1024))[tid];
    float4v r;
    #pragma unroll
    for (int c = 0; c < 4; ++c)
        r[c] = (xv[c] - mean) * rs * wv[c] + bv[c] + bf2f((unsigned short)av[c]);
    s  = r[0] + r[1] + r[2] + r[3];
    s2 = r[0]*r[0] + r[1]*r[1] + r[2]*r[2] + r[3]*r[3];
    block_reduce_2(s, s2, red);
    float mean2 = s * (1.0f / 1024.0f);
    float var2  = s2 * (1.0f / 1024.0f) - mean2 * mean2;
    float rs2   = rsqrtf(var2 + LN_EPS);
    float4v w2v = ((const float4v*)w2)[tid];
    float4v b2v = ((const float4v*)b2)[tid];
    float4v o;
    #pragma unroll
    for (int c = 0; c < 4; ++c)
        o[c] = (r[c] - mean2) * rs2 * w2v[c] + b2v[c];
    ((float4v*)(out + (size_t)row * 1024))[tid] = o;
}

// ---------------------------------------------------------------- launch
extern "C" void kernel_launch(void* const* d_in, const int* in_sizes, int n_in,
                              void* d_out, int out_size, void* d_ws, size_t ws_size,
                              hipStream_t stream) {
    const float* x    = (const float*)d_in[0];
    const float* ln1w = (const float*)d_in[1];
    const float* ln1b = (const float*)d_in[2];
    const float* inw  = (const float*)d_in[3];
    const float* inb  = (const float*)d_in[4];
    const float* ln2w = (const float*)d_in[5];
    const float* ln2b = (const float*)d_in[6];
    float* out  = (float*)d_out;
    float* avgw = out + 33554432;           // 256*128*1024

    char* ws = (char*)d_ws;                 // needs ~275 MB
    unsigned short* xnb = (unsigned short*)(ws);                 // also attnb (reused)
    unsigned short* Qb  = (unsigned short*)(ws + 67108864);
    unsigned short* Kb  = (unsigned short*)(ws + 134217728);
    unsigned short* Vb  = (unsigned short*)(ws + 201326592);
    unsigned short* Wb  = (unsigned short*)(ws + 268435456);

    k0_w_to_bf16<<<1536, 256, 0, stream>>>(inw, Wb);
    k1_ln1<<<32768, 256, 0, stream>>>(x, ln1w, ln1b, xnb);
    k2_qkv_gemm<<<1536, 512, 0, stream>>>(xnb, Wb, inb, Qb, Kb, Vb);
    k3_attn<<<4096, 256, 0, stream>>>(Qb, Kb, Vb, xnb /*attnb*/, avgw);
    k4_ln2<<<32768, 256, 0, stream>>>(x, ln1w, ln1b, xnb /*attnb*/, ln2w, ln2b, out);
}